// Round 23
// baseline (195.193 us; speedup 1.0000x reference)
//
#include <hip/hip_runtime.h>
#include <hip/hip_bf16.h>

#define BATCH 64
#define MDIM 512
#define NDIM 1024
#define KDIM 1024

#define BM 256
#define BN 256
#define BK 32               // bf16 per row-tile: 64 B = 4 x 16B slots
#define NKT (KDIM / BK)     // 32 K-tiles

typedef __attribute__((ext_vector_type(4))) float f32x4;
typedef __attribute__((ext_vector_type(8))) short bf16x8;
typedef __attribute__((ext_vector_type(4))) unsigned int u32x4;

__device__ __forceinline__ unsigned int cvt2(float lo, float hi) {
    __hip_bfloat162 h = __float22bfloat162_rn(float2{lo, hi});
    return *(unsigned int*)&h;
}

#define MFMA16(a, b, c) __builtin_amdgcn_mfma_f32_16x16x32_bf16((a), (b), (c), 0, 0, 0)
#define SB0 __builtin_amdgcn_sched_barrier(0)
#define WAITLG(n) do { asm volatile("s_waitcnt lgkmcnt(" #n ")" ::: "memory"); SB0; } while (0)
#define BAR do { SB0; __builtin_amdgcn_s_barrier(); SB0; } while (0)

// 4-buffer LDS ring: at tile kt -- read b[kt%4]; CVTW (regs loaded at kt-2)
// -> b[(kt+2)%4]; ISSUE tile kt+4. One barrier + one lgkm drain per tile.
// Seal: writes@kt drained at (kt+1)-mid WAITLG(0) (1 tile old, free),
// ordered by BAR(kt+1), read at kt+2. WAR: b[i] read@kt=i; rewritten by
// writes issued @i+2 after BAR(i+1).
__global__ __launch_bounds__(512, 2)
void grouped_fc_kernel(const float* __restrict__ X,
                       const float* __restrict__ W,
                       const float* __restrict__ Bias,
                       float* __restrict__ Out) {
    // XCD swizzle (bijective: 512 % 8 == 0)
    const int swz  = (blockIdx.x & 7) * 64 + (blockIdx.x >> 3);
    const int bidx = swz >> 3;
    const int tile = swz & 7;
    const int tm = tile & 1;
    const int tn = tile >> 1;

    const int tid  = threadIdx.x;
    const int lane = tid & 63;
    const int wid  = tid >> 6;
    const int wm   = wid & 1;      // 2 wave rows (128 out-rows)
    const int wn   = wid >> 1;     // 4 wave cols (64 out-cols)

    // [row][32] bf16 = 4 x 16B slots/row; slot s stored at s ^ ((row>>1)&3)
    // (R3/R6-measured-zero-conflict family). 4 ring buffers = 128 KB total.
    __shared__ unsigned short ldsA[4][BM][BK];
    __shared__ unsigned short ldsB[4][BN][BK];

    const float* srcA = X + ((size_t)bidx * MDIM + (size_t)tm * BM) * KDIM;
    const float* srcB = W + ((size_t)bidx * NDIM + (size_t)tn * BN) * KDIM;

    // staging: 2 threads/row, 16 fp32 each (half a 32-fp32 row), A and B
    const int s_r  = tid >> 1;             // row 0..255
    const int half = tid & 1;
    const int s_cf = half * 16;            // fp32 col offset
    const int sx   = (s_r >> 1) & 3;
    const int so0  = ((half * 2)     ^ sx) * 8;   // swizzled bf16 offsets
    const int so1  = ((half * 2 + 1) ^ sx) * 8;

    // two staging reg sets (tiles kt+2 / kt+3 in flight): 2 x 32 VGPR
    f32x4 S0[8], S1[8];

    auto ISSUE = [&](int kt_, f32x4 (&s)[8]) {
        const float* pa = srcA + (size_t)s_r * KDIM + kt_ * BK + s_cf;
        const float* pb = srcB + (size_t)s_r * KDIM + kt_ * BK + s_cf;
#pragma unroll
        for (int v = 0; v < 4; ++v) s[v]     = *(const f32x4*)(pa + v * 4);
#pragma unroll
        for (int v = 0; v < 4; ++v) s[4 + v] = *(const f32x4*)(pb + v * 4);
    };

    auto CVTW = [&](int buf, f32x4 (&s)[8]) {
        u32x4 wa0, wa1, wb0, wb1;
        wa0[0] = cvt2(s[0][0], s[0][1]); wa0[1] = cvt2(s[0][2], s[0][3]);
        wa0[2] = cvt2(s[1][0], s[1][1]); wa0[3] = cvt2(s[1][2], s[1][3]);
        wa1[0] = cvt2(s[2][0], s[2][1]); wa1[1] = cvt2(s[2][2], s[2][3]);
        wa1[2] = cvt2(s[3][0], s[3][1]); wa1[3] = cvt2(s[3][2], s[3][3]);
        wb0[0] = cvt2(s[4][0], s[4][1]); wb0[1] = cvt2(s[4][2], s[4][3]);
        wb0[2] = cvt2(s[5][0], s[5][1]); wb0[3] = cvt2(s[5][2], s[5][3]);
        wb1[0] = cvt2(s[6][0], s[6][1]); wb1[1] = cvt2(s[6][2], s[6][3]);
        wb1[2] = cvt2(s[7][0], s[7][1]); wb1[3] = cvt2(s[7][2], s[7][3]);
        *(u32x4*)&ldsA[buf][s_r][so0] = wa0;
        *(u32x4*)&ldsA[buf][s_r][so1] = wa1;
        *(u32x4*)&ldsB[buf][s_r][so0] = wb0;
        *(u32x4*)&ldsB[buf][s_r][so1] = wb1;
    };

    // frag reads: frag base rows 16-aligned -> (row>>1)&3 == (frow>>1)&3
    const int frow = lane & 15;
    const int khi  = lane >> 4;            // k-slot 0..3
    const int rsl  = (khi ^ ((frow >> 1) & 3)) * 8;

    auto rdA = [&](int buf, int mi) {
        return *(const bf16x8*)&ldsA[buf][wm * 128 + mi * 16 + frow][rsl];
    };
    auto rdB = [&](int buf, int ni) {
        return *(const bf16x8*)&ldsB[buf][wn * 64 + ni * 16 + frow][rsl];
    };

    f32x4 acc[8][4];
#pragma unroll
    for (int mi = 0; mi < 8; ++mi)
#pragma unroll
        for (int ni = 0; ni < 4; ++ni)
            acc[mi][ni] = (f32x4){0.f, 0.f, 0.f, 0.f};

    // ---- prologue: tiles 0,1 -> b0,b1; tiles 2,3 -> reg sets ----
    ISSUE(0, S0); CVTW(0, S0);
    ISSUE(1, S0); CVTW(1, S0);
    ISSUE(2, S0); ISSUE(3, S1);
    WAITLG(0);
    BAR;

    bf16x8 af[8], bfr[4];

#pragma unroll 1
    for (int kt = 0; kt < NKT; ++kt) {
        const int rd = kt & 3;

        // frag reads (12 x ds_read_b128)
#pragma unroll
        for (int mi = 0; mi < 8; ++mi) af[mi] = rdA(rd, mi);
#pragma unroll
        for (int ni = 0; ni < 4; ++ni) bfr[ni] = rdB(rd, ni);
        // drains: our reads + last tile's 4 writes (1 tile old -> free)
        WAITLG(0);

        __builtin_amdgcn_s_setprio(1);
#pragma unroll
        for (int mi = 0; mi < 8; ++mi)
#pragma unroll
            for (int ni = 0; ni < 4; ++ni)
                acc[mi][ni] = MFMA16(af[mi], bfr[ni], acc[mi][ni]);
        __builtin_amdgcn_s_setprio(0);
        SB0;

        // publish tile kt+2 (regs 2 tiles in flight); issue tile kt+4
        if (kt < NKT - 2) CVTW((kt + 2) & 3, (kt & 1) ? S1 : S0);
        if (kt < NKT - 4) ISSUE(kt + 4, (kt & 1) ? S1 : S0);

        BAR;    // orders last tile's drained writes for next tile's readers
    }

    // epilogue: acc layout col=lane&15, row=(lane>>4)*4+r (m89-verified)
#pragma unroll
    for (int ni = 0; ni < 4; ++ni) {
        const int gc = tn * BN + wn * 64 + ni * 16 + frow;
        const float bv = Bias[bidx * NDIM + gc];
#pragma unroll
        for (int mi = 0; mi < 8; ++mi) {
            const int gr0 = tm * BM + wm * 128 + mi * 16 + khi * 4;
            float* po = Out + ((size_t)bidx * MDIM + gr0) * NDIM + gc;
#pragma unroll
            for (int r = 0; r < 4; ++r)
                po[(size_t)r * NDIM] = acc[mi][ni][r] + bv;
        }
    }
}

extern "C" void kernel_launch(void* const* d_in, const int* in_sizes, int n_in,
                              void* d_out, int out_size, void* d_ws, size_t ws_size,
                              hipStream_t stream) {
    const float* X  = (const float*)d_in[0];
    const float* W  = (const float*)d_in[1];
    const float* Bs = (const float*)d_in[2];
    float* Out = (float*)d_out;

    grouped_fc_kernel<<<dim3(512), dim3(512), 0, stream>>>(X, W, Bs, Out);
}

// Round 24
// 154.532 us; speedup vs baseline: 1.2631x; 1.2631x over previous
//
#include <hip/hip_runtime.h>
#include <hip/hip_bf16.h>

#define BATCH 64
#define MDIM 512
#define NDIM 1024
#define KDIM 1024

#define BM 256
#define BN 256
#define BK 64
#define NKT (KDIM / BK)     // 16 K-tiles

typedef __attribute__((ext_vector_type(4))) float f32x4;
typedef __attribute__((ext_vector_type(8))) short bf16x8;
typedef __attribute__((ext_vector_type(4))) unsigned int u32x4;

__device__ __forceinline__ unsigned int cvt2(float lo, float hi) {
    __hip_bfloat162 h = __float22bfloat162_rn(float2{lo, hi});
    return *(unsigned int*)&h;
}

#define MFMA16(a, b, c) __builtin_amdgcn_mfma_f32_16x16x32_bf16((a), (b), (c), 0, 0, 0)
#define SB0 __builtin_amdgcn_sched_barrier(0)
// Inline-asm wait is used ONLY as the release edge before the tile-seal
// barrier (rule 18: SB0 right after). Read->MFMA waits are left to the
// compiler, which emits fine-grained counted lgkmcnt (m97 asm evidence).
#define WAITLG0 do { asm volatile("s_waitcnt lgkmcnt(0)" ::: "memory"); SB0; } while (0)
#define BAR do { SB0; __builtin_amdgcn_s_barrier(); SB0; } while (0)

__global__ __launch_bounds__(512, 2)
void grouped_fc_kernel(const float* __restrict__ X,
                       const float* __restrict__ W,
                       const float* __restrict__ Bias,
                       float* __restrict__ Out) {
    // XCD swizzle (bijective: 512 % 8 == 0)
    const int swz  = (blockIdx.x & 7) * 64 + (blockIdx.x >> 3);
    const int bidx = swz >> 3;
    const int tile = swz & 7;
    const int tm = tile & 1;
    const int tn = tile >> 1;

    const int tid  = threadIdx.x;
    const int lane = tid & 63;
    const int wid  = tid >> 6;
    const int wm   = wid & 1;      // 2 wave rows (128 out-rows)
    const int wn   = wid >> 1;     // 4 wave cols (64 out-cols)

    // [row][64] bf16 = 8 x 16B slots/row; slot s at s ^ (row&7).
    // R9/R13/R21-measured: SQ_LDS_BANK_CONFLICT == 0.
    __shared__ unsigned short ldsA[2][BM][BK];
    __shared__ unsigned short ldsB[2][BN][BK];

    const float* srcA = X + ((size_t)bidx * MDIM + (size_t)tm * BM) * KDIM;
    const float* srcB = W + ((size_t)bidx * NDIM + (size_t)tn * BN) * KDIM;

    // staging: 4 threads/row, 16 fp32 each, per 128-row half-tile
    const int s_r  = tid >> 2;
    const int s_cf = (tid & 3) * 16;
    const int s_x  = s_r & 7;
    const int so0  = (((tid & 3) * 2)     ^ s_x) * 8;
    const int so1  = (((tid & 3) * 2 + 1) ^ s_x) * 8;

    f32x4 st0[4], st1[4];

    auto ISSUE = [&](const float* srcbase, int hv, int kt_, f32x4 (&s)[4]) {
        const float* p = srcbase + (size_t)(hv * 128 + s_r) * KDIM + kt_ * BK + s_cf;
#pragma unroll
        for (int v = 0; v < 4; ++v) s[v] = *(const f32x4*)(p + v * 4);
    };

    auto CVTW = [&](unsigned short* ldsbase, int hv, f32x4 (&s)[4]) {
        const int row = hv * 128 + s_r;
        u32x4 w0, w1;
        w0[0] = cvt2(s[0][0], s[0][1]); w0[1] = cvt2(s[0][2], s[0][3]);
        w0[2] = cvt2(s[1][0], s[1][1]); w0[3] = cvt2(s[1][2], s[1][3]);
        w1[0] = cvt2(s[2][0], s[2][1]); w1[1] = cvt2(s[2][2], s[2][3]);
        w1[2] = cvt2(s[3][0], s[3][1]); w1[3] = cvt2(s[3][2], s[3][3]);
        *(u32x4*)&ldsbase[(size_t)row * BK + so0] = w0;
        *(u32x4*)&ldsbase[(size_t)row * BK + so1] = w1;
    };

    // frag reads: row&7 == frow&7 (frag base rows are multiples of 8)
    const int frow = lane & 15;
    const int khi  = lane >> 4;
    const int xr   = frow & 7;
    const int oK0  = ((khi)     ^ xr) * 8;
    const int oK1  = ((4 + khi) ^ xr) * 8;

    auto rdA = [&](int buf, int mi, int o) {
        return *(const bf16x8*)&ldsA[buf][wm * 128 + mi * 16 + frow][o];
    };
    auto rdB = [&](int buf, int ni, int o) {
        return *(const bf16x8*)&ldsB[buf][wn * 64 + ni * 16 + frow][o];
    };

    f32x4 acc[8][4];
#pragma unroll
    for (int mi = 0; mi < 8; ++mi)
#pragma unroll
        for (int ni = 0; ni < 4; ++ni)
            acc[mi][ni] = (f32x4){0.f, 0.f, 0.f, 0.f};

    // ---- prologue: stage tile 0 -> buf0; issue tile-1 A halves ----
    ISSUE(srcA, 0, 0, st0); ISSUE(srcA, 1, 0, st1);
    CVTW(&ldsA[0][0][0], 0, st0); CVTW(&ldsA[0][0][0], 1, st1);
    ISSUE(srcB, 0, 0, st0); ISSUE(srcB, 1, 0, st1);
    CVTW(&ldsB[0][0][0], 0, st0); CVTW(&ldsB[0][0][0], 1, st1);
    ISSUE(srcA, 0, 1, st0); ISSUE(srcA, 1, 1, st1);
    WAITLG0;
    BAR;

    bf16x8 af[8], bfr[4];

    // main loop: 4 pacing barriers/tile (R13-proven); read->MFMA waits are
    // compiler-managed fine-grained lgkmcnt; single manual release drain
    // before the tile-seal barrier.
#pragma unroll 1
    for (int kt = 0; kt < NKT - 1; ++kt) {
        const int rd = kt & 1;
        const bool m2 = (kt + 2 < NKT);
        unsigned short* nA = &ldsA[rd ^ 1][0][0];
        unsigned short* nB = &ldsB[rd ^ 1][0][0];

        // ---- P0 ----
#pragma unroll
        for (int mi = 0; mi < 8; ++mi) af[mi] = rdA(rd, mi, oK0);
        bfr[0] = rdB(rd, 0, oK0); bfr[1] = rdB(rd, 1, oK0);
        __builtin_amdgcn_s_setprio(1);
#pragma unroll
        for (int mi = 0; mi < 8; ++mi) {
            acc[mi][0] = MFMA16(af[mi], bfr[0], acc[mi][0]);
            acc[mi][1] = MFMA16(af[mi], bfr[1], acc[mi][1]);
        }
        __builtin_amdgcn_s_setprio(0);
        bfr[2] = rdB(rd, 2, oK0); bfr[3] = rdB(rd, 3, oK0);
        CVTW(nA, 0, st0);
        ISSUE(srcB, 0, kt + 1, st0);
        BAR;

        // ---- P1 ----
        __builtin_amdgcn_s_setprio(1);
#pragma unroll
        for (int mi = 0; mi < 8; ++mi) {
            acc[mi][2] = MFMA16(af[mi], bfr[2], acc[mi][2]);
            acc[mi][3] = MFMA16(af[mi], bfr[3], acc[mi][3]);
        }
        __builtin_amdgcn_s_setprio(0);
#pragma unroll
        for (int mi = 0; mi < 8; ++mi) af[mi] = rdA(rd, mi, oK1);
        bfr[0] = rdB(rd, 0, oK1); bfr[1] = rdB(rd, 1, oK1);
        CVTW(nA, 1, st1);
        ISSUE(srcB, 1, kt + 1, st1);
        BAR;

        // ---- P2 ----
        __builtin_amdgcn_s_setprio(1);
#pragma unroll
        for (int mi = 0; mi < 8; ++mi) {
            acc[mi][0] = MFMA16(af[mi], bfr[0], acc[mi][0]);
            acc[mi][1] = MFMA16(af[mi], bfr[1], acc[mi][1]);
        }
        __builtin_amdgcn_s_setprio(0);
        bfr[2] = rdB(rd, 2, oK1); bfr[3] = rdB(rd, 3, oK1);
        CVTW(nB, 0, st0); CVTW(nB, 1, st1);
        if (m2) ISSUE(srcA, 0, kt + 2, st0);
        BAR;

        // ---- P3 + tile seal ----
        __builtin_amdgcn_s_setprio(1);
#pragma unroll
        for (int mi = 0; mi < 8; ++mi) {
            acc[mi][2] = MFMA16(af[mi], bfr[2], acc[mi][2]);
            acc[mi][3] = MFMA16(af[mi], bfr[3], acc[mi][3]);
        }
        __builtin_amdgcn_s_setprio(0);
        if (m2) ISSUE(srcA, 1, kt + 2, st1);
        WAITLG0;                        // release: all ds_writes drained
        BAR;                            // buf^1 sealed
    }

    // ---- peeled last tile (no staging) ----
    {
        const int rd = (NKT - 1) & 1;
#pragma unroll
        for (int mi = 0; mi < 8; ++mi) af[mi] = rdA(rd, mi, oK0);
#pragma unroll
        for (int ni = 0; ni < 4; ++ni) bfr[ni] = rdB(rd, ni, oK0);
#pragma unroll
        for (int mi = 0; mi < 8; ++mi)
#pragma unroll
            for (int ni = 0; ni < 4; ++ni)
                acc[mi][ni] = MFMA16(af[mi], bfr[ni], acc[mi][ni]);
#pragma unroll
        for (int mi = 0; mi < 8; ++mi) af[mi] = rdA(rd, mi, oK1);
#pragma unroll
        for (int ni = 0; ni < 4; ++ni) bfr[ni] = rdB(rd, ni, oK1);
#pragma unroll
        for (int mi = 0; mi < 8; ++mi)
#pragma unroll
            for (int ni = 0; ni < 4; ++ni)
                acc[mi][ni] = MFMA16(af[mi], bfr[ni], acc[mi][ni]);
    }

    // epilogue: acc layout col=lane&15, row=(lane>>4)*4+r (m89-verified)
#pragma unroll
    for (int ni = 0; ni < 4; ++ni) {
        const int gc = tn * BN + wn * 64 + ni * 16 + frow;
        const float bv = Bias[bidx * NDIM + gc];
#pragma unroll
        for (int mi = 0; mi < 8; ++mi) {
            const int gr0 = tm * BM + wm * 128 + mi * 16 + khi * 4;
            float* po = Out + ((size_t)bidx * MDIM + gr0) * NDIM + gc;
#pragma unroll
            for (int r = 0; r < 4; ++r)
                po[(size_t)r * NDIM] = acc[mi][ni][r] + bv;
        }
    }
}

extern "C" void kernel_launch(void* const* d_in, const int* in_sizes, int n_in,
                              void* d_out, int out_size, void* d_ws, size_t ws_size,
                              hipStream_t stream) {
    const float* X  = (const float*)d_in[0];
    const float* W  = (const float*)d_in[1];
    const float* Bs = (const float*)d_in[2];
    float* Out = (float*)d_out;

    grouped_fc_kernel<<<dim3(512), dim3(512), 0, stream>>>(X, W, Bs, Out);
}